// Round 2
// 1322.213 us; speedup vs baseline: 1.5881x; 1.5881x over previous
//
#include <hip/hip_runtime.h>
#include <hip/hip_bf16.h>

#define NN 10000
#define INDIM 256
#define HIDDIM 64

typedef __hip_bfloat16 bf16;
typedef unsigned short u16;
typedef __attribute__((ext_vector_type(8))) short bf16x8;
typedef __attribute__((ext_vector_type(4))) float f32x4;

// ---------------- runtime dtype sniffing ----------------
// flags[0]: 1 if float tensors are bf16, 0 if float32
// flags[1]: 1 if edge_index is int64, 0 if int32
__global__ void k_sniff(const unsigned* __restrict__ xw, const unsigned* __restrict__ ew,
                        int* __restrict__ flags) {
    if (threadIdx.x == 0 && blockIdx.x == 0) {
        int c = 0;
        for (int j = 0; j < 256; ++j) {
            unsigned e = (xw[j] >> 7) & 0xFF;   // exponent field of low-half-as-bf16
            c += (e >= 0x74 && e <= 0x85);      // |v| in [2^-11, 2^6]: ~99% for bf16 N(0,1), ~7% for f32 mantissa bits
        }
        flags[0] = (c >= 128);
        int z = 0;
        for (int j = 0; j < 128; ++j) z += (ew[2 * j + 1] == 0u);  // int64 high words
        flags[1] = (z >= 64);
    }
}

__global__ void k_cvt(const void* __restrict__ in, float* __restrict__ out, int n,
                      const int* __restrict__ flags) {
    int i = blockIdx.x * 256 + threadIdx.x;
    if (i >= n) return;
    if (flags[0]) out[i] = __bfloat162float(((const bf16*)in)[i]);
    else          out[i] = ((const float*)in)[i];
}

__global__ void k_cvt_idx(const void* __restrict__ ei, int* __restrict__ s32,
                          int* __restrict__ d32, int E, const int* __restrict__ flags) {
    int e = blockIdx.x * 256 + threadIdx.x;
    if (e >= E) return;
    if (flags[1]) {
        const long long* p = (const long long*)ei;
        s32[e] = (int)p[e]; d32[e] = (int)p[e + E];
    } else {
        const int* p = (const int*)ei;
        s32[e] = p[e]; d32[e] = p[e + E];
    }
}

// ---------------- gcn_norm ----------------

__global__ void k_init_deg(float* deg) {
    int i = blockIdx.x * 256 + threadIdx.x;
    if (i < NN) deg[i] = 1.0f;   // self-loop weight
}

__global__ void k_edge_deg(const int* __restrict__ src, const int* __restrict__ dst,
                           float* __restrict__ deg, int E) {
    int e = blockIdx.x * 256 + threadIdx.x;
    if (e < E) {
        int s = src[e], d = dst[e];
        if (s != d) atomicAdd(&deg[d], 1.0f);   // existing self-loops get weight 0
    }
}

__global__ void k_dinv(float* deg, float* selfn) {
    int i = blockIdx.x * 256 + threadIdx.x;
    if (i < NN) {
        float dv = 1.0f / sqrtf(deg[i]);   // deg >= 1 always
        deg[i] = dv;                       // deg buffer becomes dinv
        selfn[i] = dv * dv;
    }
}

__global__ void k_edge_norm(const int* __restrict__ src, const int* __restrict__ dst,
                            const float* __restrict__ dinv, float* __restrict__ nrm, int E) {
    int e = blockIdx.x * 256 + threadIdx.x;
    if (e < E) {
        int s = src[e], d = dst[e];
        nrm[e] = (s != d) ? dinv[s] * dinv[d] : 0.0f;
    }
}

// ---------------- dense GEMMs (fp32 VALU — all are tiny: <=0.33 GFLOP) ----------------
// block (64,4): wave = one row i, 64 consecutive j

template <int K, int NOUT>
__global__ void k_gemm(const float* __restrict__ A, const float* __restrict__ W,
                       float* __restrict__ out) {
    int j = blockIdx.x * 64 + threadIdx.x;
    int i = blockIdx.y * 4 + threadIdx.y;
    const float* arow = A + (size_t)i * K;
    float acc = 0.0f;
#pragma unroll 8
    for (int k = 0; k < K; ++k)
        acc = fmaf(arow[k], W[k * NOUT + j], acc);
    out[(size_t)i * NOUT + j] = acc;
}

template <int K, int NOUT, bool RELU>
__global__ void k_gemm_bias(const float* __restrict__ A, const float* __restrict__ W,
                            const float* __restrict__ b, float* __restrict__ out) {
    int j = blockIdx.x * 64 + threadIdx.x;
    int i = blockIdx.y * 4 + threadIdx.y;
    const float* arow = A + (size_t)i * K;
    float acc = b[j];
#pragma unroll 8
    for (int k = 0; k < K; ++k)
        acc = fmaf(arow[k], W[k * NOUT + j], acc);
    if (RELU) acc = fmaxf(acc, 0.0f);
    out[(size_t)i * NOUT + j] = acc;
}

// conv5 GEMM fused with bf16 hi/lo split of hs
__global__ void k_gemm_split(const float* __restrict__ A, const float* __restrict__ W,
                             const float* __restrict__ b,
                             u16* __restrict__ hi, u16* __restrict__ lo) {
    int j = blockIdx.x * 64 + threadIdx.x;
    int i = blockIdx.y * 4 + threadIdx.y;
    size_t o = (size_t)i * 256 + j;
    const float* arow = A + (size_t)i * 64;
    float acc = b[j];
#pragma unroll 8
    for (int k = 0; k < 64; ++k)
        acc = fmaf(arow[k], W[k * 256 + j], acc);
    bf16 h = __float2bfloat16(acc);
    float hf = __bfloat162float(h);
    bf16 l = __float2bfloat16(acc - hf);
    hi[o] = *(const u16*)&h;
    lo[o] = *(const u16*)&l;
}

// conv4 GEMM writing x_ with runtime out dtype
__global__ void k_gemm_out(const float* __restrict__ A, const float* __restrict__ W,
                           const float* __restrict__ b, void* __restrict__ out,
                           const int* __restrict__ flags) {
    int j = blockIdx.x * 64 + threadIdx.x;
    int i = blockIdx.y * 4 + threadIdx.y;
    const float* arow = A + (size_t)i * 64;
    float acc = b[j];
#pragma unroll 8
    for (int k = 0; k < 64; ++k)
        acc = fmaf(arow[k], W[k * 256 + j], acc);
    size_t o = (size_t)i * 256 + j;
    if (flags[0]) ((bf16*)out)[o] = __float2bfloat16(acc);
    else          ((float*)out)[o] = acc;
}

// ---------------- aggregation (all 64-wide now) ----------------

template <int F>
__global__ void k_agg_init(const float* __restrict__ xw, const float* __restrict__ selfn,
                           float* __restrict__ agg) {
    int t = blockIdx.x * 256 + threadIdx.x;
    int i = t / F;
    agg[t] = selfn[i] * xw[t];
}

template <int F>
__global__ void k_scatter(const int* __restrict__ src, const int* __restrict__ dst,
                          const float* __restrict__ nrm, const float* __restrict__ xw,
                          float* __restrict__ agg, int E) {
    int e = blockIdx.x * 4 + (threadIdx.x >> 6);
    int lane = threadIdx.x & 63;
    if (e < E) {
        float w = nrm[e];
        if (w != 0.0f) {
            const float* xs = xw + (size_t)src[e] * F;
            float* ad = agg + (size_t)dst[e] * F;
#pragma unroll
            for (int r = 0; r < F / 64; ++r) {
                int f = r * 64 + lane;
                atomicAdd(ad + f, w * xs[f]);
            }
        }
    }
}

template <int F, bool RELU>
__global__ void k_finalize_f32(const float* __restrict__ agg, const float* __restrict__ b,
                               float* __restrict__ out) {
    int t = blockIdx.x * 256 + threadIdx.x;
    float v = agg[t] + b[t & (F - 1)];
    if (RELU) v = fmaxf(v, 0.0f);
    out[t] = v;
}

// ---------------- adj = hs @ hs^T via split-bf16 MFMA ----------------
// hs = hi + lo (two bf16 arrays, [NN][256]).
// C = Ahi·Bhi^T + Ahi·Blo^T + Alo·Bhi^T  (lo·lo term ~2^-18 relative, dropped).
// Block 256 thr = 4 waves in 2x2; block tile 128x128, wave tile 64x64 = 4x4 MFMA tiles.
// NT layout: both operands row-major [row][K]; lane l loads row (l&15), 8 contig K at (l>>4)*8.
// Out-of-range fragment rows clamp to row NN-1 (valid data); their acc values are
// never written (i/j guards). adj is symmetric -> C/D-transpose-safe.

__global__ __launch_bounds__(256) void k_adj_mfma(const u16* __restrict__ hi,
                                                  const u16* __restrict__ lo,
                                                  void* __restrict__ d_out,
                                                  const int* __restrict__ flags) {
    int wid  = threadIdx.x >> 6;
    int lane = threadIdx.x & 63;
    int wr = wid >> 1, wc = wid & 1;
    int row0 = blockIdx.y * 128 + wr * 64;
    int col0 = blockIdx.x * 128 + wc * 64;
    int lr  = lane & 15;
    int klo = (lane >> 4) * 8;

    int aoff[4], boff[4];
#pragma unroll
    for (int u = 0; u < 4; ++u) {
        int r = row0 + u * 16 + lr; if (r > NN - 1) r = NN - 1;
        aoff[u] = r * 256 + klo;
        int c = col0 + u * 16 + lr; if (c > NN - 1) c = NN - 1;
        boff[u] = c * 256 + klo;
    }

    f32x4 acc[4][4] = {};
    for (int k0 = 0; k0 < 256; k0 += 32) {
        bf16x8 ah[4], al[4], bh[4], bl[4];
#pragma unroll
        for (int u = 0; u < 4; ++u) {
            ah[u] = *(const bf16x8*)(hi + aoff[u] + k0);
            al[u] = *(const bf16x8*)(lo + aoff[u] + k0);
            bh[u] = *(const bf16x8*)(hi + boff[u] + k0);
            bl[u] = *(const bf16x8*)(lo + boff[u] + k0);
        }
#pragma unroll
        for (int u = 0; u < 4; ++u)
#pragma unroll
            for (int v = 0; v < 4; ++v) {
                acc[u][v] = __builtin_amdgcn_mfma_f32_16x16x32_bf16(ah[u], bh[v], acc[u][v], 0, 0, 0);
                acc[u][v] = __builtin_amdgcn_mfma_f32_16x16x32_bf16(ah[u], bl[v], acc[u][v], 0, 0, 0);
                acc[u][v] = __builtin_amdgcn_mfma_f32_16x16x32_bf16(al[u], bh[v], acc[u][v], 0, 0, 0);
            }
    }

    int obf = flags[0];
    int cr = (lane >> 4) * 4;
    int cc = lane & 15;
    bf16*  ob = (bf16*)d_out + (size_t)NN * INDIM;
    float* of = (float*)d_out + (size_t)NN * INDIM;
#pragma unroll
    for (int u = 0; u < 4; ++u) {
#pragma unroll
        for (int r = 0; r < 4; ++r) {
            int i = row0 + u * 16 + cr + r;
            if (i >= NN) continue;
#pragma unroll
            for (int v = 0; v < 4; ++v) {
                int j = col0 + v * 16 + cc;
                if (j >= NN) continue;
                float val = acc[u][v][r];
                if (obf) ob[(size_t)i * NN + j] = __float2bfloat16(val);
                else     of[(size_t)i * NN + j] = val;
            }
        }
    }
}

// ---------------- driver ----------------
// Reordering trick used throughout: A·(H W) = (A·H)·W, so ALL scatters run at
// width 64 (was: two at width 256), and A·h2 is shared by conv3 and conv5.

extern "C" void kernel_launch(void* const* d_in, const int* in_sizes, int n_in,
                              void* d_out, int out_size, void* d_ws, size_t ws_size,
                              hipStream_t stream) {
    const void* x_raw  = d_in[0];
    const void* ei_raw = d_in[1];

    const int E = in_sizes[1] / 2;

    // ---- d_ws layout (identical footprint to verified round-0: 14,426,240 B) ----
    int*   flags = (int*)d_ws;
    float* wsf   = (float*)d_ws;
    float* deg   = wsf + 16;        // 10000 (reserve 10240)
    float* selfn = wsf + 10256;     // 10000 (reserve 10240)
    float* nrm   = wsf + 20496;     // E (reserve 327680)
    int*   s32   = (int*)(wsf + 348176);   // E
    int*   d32   = (int*)(wsf + 668176);   // E
    float* w32   = wsf + 988176;    // 58048 fp32 weights/biases
    u16*   hs_hi = (u16*)(wsf + 1046560);  // NN*256 bf16 (1,280,000 floats worth)
    u16*   hs_lo = hs_hi + (size_t)NN * 256;  // NN*256 bf16

    float* encW1 = w32 + 0;
    float* encb1 = w32 + 16384;
    float* encW2 = w32 + 16448;
    float* encb2 = w32 + 20544;
    float* attW1 = w32 + 20608;
    float* attb1 = w32 + 24704;
    float* attW2 = w32 + 24768;
    float* attb2 = w32 + 41152;
    float* stW   = w32 + 41408;
    float* stb   = w32 + 57792;

    // ---- large scratch inside adj output region (dead before k_adj writes it) ----
    float* osc  = (float*)((char*)d_out + 16000000);  // 16 MB byte offset, 16B aligned
    float* x32  = osc;                 // NN*256
    float* bufA = osc + 2560000;       // NN*64 (xw)
    float* bufB = osc + 5120000;       // NN*64 (aggregation buffer, reused 4x)
    float* h1   = osc + 7680000;       // NN*64
    float* h2   = osc + 8320000;       // NN*64
    float* a1   = osc + 8960000;       // NN*64

    int eb  = (E + 255) / 256;
    int ewb = (E + 3) / 4;

    k_sniff<<<1, 64, 0, stream>>>((const unsigned*)x_raw, (const unsigned*)ei_raw, flags);

    // convert inputs to fp32 / int32
    k_cvt<<<10000, 256, 0, stream>>>(x_raw, x32, NN * INDIM, flags);
    k_cvt<<<64, 256, 0, stream>>>(d_in[2],  encW1, 16384, flags);
    k_cvt<<<1, 256, 0, stream>>>(d_in[3],   encb1, 64, flags);
    k_cvt<<<16, 256, 0, stream>>>(d_in[4],  encW2, 4096, flags);
    k_cvt<<<1, 256, 0, stream>>>(d_in[5],   encb2, 64, flags);
    k_cvt<<<16, 256, 0, stream>>>(d_in[6],  attW1, 4096, flags);
    k_cvt<<<1, 256, 0, stream>>>(d_in[7],   attb1, 64, flags);
    k_cvt<<<64, 256, 0, stream>>>(d_in[8],  attW2, 16384, flags);
    k_cvt<<<1, 256, 0, stream>>>(d_in[9],   attb2, 256, flags);
    k_cvt<<<64, 256, 0, stream>>>(d_in[10], stW, 16384, flags);
    k_cvt<<<1, 256, 0, stream>>>(d_in[11],  stb, 256, flags);
    k_cvt_idx<<<eb, 256, 0, stream>>>(ei_raw, s32, d32, E, flags);

    // gcn_norm
    k_init_deg<<<40, 256, 0, stream>>>(deg);
    k_edge_deg<<<eb, 256, 0, stream>>>(s32, d32, deg, E);
    k_dinv<<<40, 256, 0, stream>>>(deg, selfn);
    k_edge_norm<<<eb, 256, 0, stream>>>(s32, d32, deg, nrm, E);

    // conv1: h1 = relu(A·(x @ encW1) + b1)   (project 256->64 first, then aggregate)
    k_gemm<256, 64><<<dim3(1, 2500), dim3(64, 4), 0, stream>>>(x32, encW1, bufA);
    k_agg_init<64><<<2500, 256, 0, stream>>>(bufA, selfn, bufB);
    k_scatter<64><<<ewb, 256, 0, stream>>>(s32, d32, nrm, bufA, bufB, E);
    k_finalize_f32<64, true><<<2500, 256, 0, stream>>>(bufB, encb1, h1);

    // conv2 (reordered): h2 = (A·h1) @ encW2 + b2
    k_agg_init<64><<<2500, 256, 0, stream>>>(h1, selfn, bufB);
    k_scatter<64><<<ewb, 256, 0, stream>>>(s32, d32, nrm, h1, bufB, E);
    k_gemm_bias<64, 64, false><<<dim3(1, 2500), dim3(64, 4), 0, stream>>>(bufB, encW2, encb2, h2);

    // conv3 + conv5 share ah2 = A·h2:
    //   a1 = relu(ah2 @ attW1 + attb1)
    //   hs = ah2 @ stW + stb  -> split to bf16 hi/lo directly
    k_agg_init<64><<<2500, 256, 0, stream>>>(h2, selfn, bufB);
    k_scatter<64><<<ewb, 256, 0, stream>>>(s32, d32, nrm, h2, bufB, E);
    k_gemm_bias<64, 64, true><<<dim3(1, 2500), dim3(64, 4), 0, stream>>>(bufB, attW1, attb1, a1);
    k_gemm_split<<<dim3(4, 2500), dim3(64, 4), 0, stream>>>(bufB, stW, stb, hs_hi, hs_lo);

    // conv4 (reordered): x_ = (A·a1) @ attW2 + attb2   (runtime out dtype)
    k_agg_init<64><<<2500, 256, 0, stream>>>(a1, selfn, bufB);
    k_scatter<64><<<ewb, 256, 0, stream>>>(s32, d32, nrm, a1, bufB, E);
    k_gemm_out<<<dim3(4, 2500), dim3(64, 4), 0, stream>>>(bufB, attW2, attb2, d_out, flags);

    // adj = hs @ hs^T  (MFMA, split-bf16; reads only d_ws, writes whole adj region)
    k_adj_mfma<<<dim3(79, 79), 256, 0, stream>>>(hs_hi, hs_lo, d_out, flags);
}

// Round 3
// 1065.937 us; speedup vs baseline: 1.9699x; 1.2404x over previous
//
#include <hip/hip_runtime.h>
#include <hip/hip_bf16.h>

#define NN 10000
#define INDIM 256
#define HIDDIM 64

typedef __hip_bfloat16 bf16;
typedef unsigned short u16;
typedef __attribute__((ext_vector_type(8))) short bf16x8;
typedef __attribute__((ext_vector_type(4))) float f32x4;
typedef __attribute__((ext_vector_type(4))) unsigned short u16x4;

// ---------------- runtime dtype sniffing ----------------
// flags[0]: 1 if float tensors are bf16, 0 if float32
// flags[1]: 1 if edge_index is int64, 0 if int32
__global__ void k_sniff(const unsigned* __restrict__ xw, const unsigned* __restrict__ ew,
                        int* __restrict__ flags) {
    if (threadIdx.x == 0 && blockIdx.x == 0) {
        int c = 0;
        for (int j = 0; j < 256; ++j) {
            unsigned e = (xw[j] >> 7) & 0xFF;
            c += (e >= 0x74 && e <= 0x85);
        }
        flags[0] = (c >= 128);
        int z = 0;
        for (int j = 0; j < 128; ++j) z += (ew[2 * j + 1] == 0u);
        flags[1] = (z >= 64);
    }
}

__global__ void k_cvt(const void* __restrict__ in, float* __restrict__ out, int n,
                      const int* __restrict__ flags) {
    int i = blockIdx.x * 256 + threadIdx.x;
    if (i >= n) return;
    if (flags[0]) out[i] = __bfloat162float(((const bf16*)in)[i]);
    else          out[i] = ((const float*)in)[i];
}

__global__ void k_zero(int* __restrict__ p, int n) {
    int i = blockIdx.x * 256 + threadIdx.x;
    if (i < n) p[i] = 0;
}

// convert edge index to int32 AND count non-self in-degree (cnt pre-zeroed)
__global__ void k_cvt_idx_count(const void* __restrict__ ei, int* __restrict__ s32,
                                int* __restrict__ d32, int* __restrict__ cnt,
                                int E, const int* __restrict__ flags) {
    int e = blockIdx.x * 256 + threadIdx.x;
    if (e >= E) return;
    int s, d;
    if (flags[1]) {
        const long long* p = (const long long*)ei;
        s = (int)p[e]; d = (int)p[e + E];
    } else {
        const int* p = (const int*)ei;
        s = p[e]; d = p[e + E];
    }
    s32[e] = s; d32[e] = d;
    if (s != d) atomicAdd(&cnt[d], 1);
}

// single block: exclusive scan of cnt -> off/cur; deg = cnt+1 -> dinv, selfn
__global__ void k_scan(const int* __restrict__ cnt, int* __restrict__ off,
                       int* __restrict__ cur, float* __restrict__ dinv,
                       float* __restrict__ selfn) {
    __shared__ int sums[256];
    int t = threadIdx.x;
    int base = t * 40;                      // 256*40 = 10240 >= NN
    int s = 0;
    if (base < NN) {
        int hi = base + 40; if (hi > NN) hi = NN;
        for (int i = base; i < hi; ++i) s += cnt[i];
    }
    sums[t] = s;
    __syncthreads();
    for (int d = 1; d < 256; d <<= 1) {     // Hillis-Steele inclusive scan
        int v = (t >= d) ? sums[t - d] : 0;
        __syncthreads();
        sums[t] += v;
        __syncthreads();
    }
    int run = t ? sums[t - 1] : 0;          // exclusive prefix for this chunk
    if (base < NN) {
        int hi = base + 40; if (hi > NN) hi = NN;
        for (int i = base; i < hi; ++i) {
            off[i] = run; cur[i] = run;
            int dg = cnt[i] + 1;            // +1 self-loop
            float dv = rsqrtf((float)dg);
            dinv[i] = dv;
            selfn[i] = 1.0f / (float)dg;
            run += cnt[i];
        }
    }
    if (t == 255) off[NN] = sums[255];
}

__global__ void k_fill(const int* __restrict__ s32, const int* __restrict__ d32,
                       int* __restrict__ cur, int* __restrict__ csr, int E) {
    int e = blockIdx.x * 256 + threadIdx.x;
    if (e < E) {
        int s = s32[e], d = d32[e];
        if (s != d) {
            int p = atomicAdd(&cur[d], 1);
            csr[p] = s;
        }
    }
}

// ---------------- dense GEMMs (fp32 VALU, all tiny) ----------------

template <int K, int NOUT>
__global__ void k_gemm(const float* __restrict__ A, const float* __restrict__ W,
                       float* __restrict__ out) {
    int j = blockIdx.x * 64 + threadIdx.x;
    int i = blockIdx.y * 4 + threadIdx.y;
    const float* arow = A + (size_t)i * K;
    float acc = 0.0f;
#pragma unroll 8
    for (int k = 0; k < K; ++k)
        acc = fmaf(arow[k], W[k * NOUT + j], acc);
    out[(size_t)i * NOUT + j] = acc;
}

template <int K, int NOUT, bool RELU>
__global__ void k_gemm_bias(const float* __restrict__ A, const float* __restrict__ W,
                            const float* __restrict__ b, float* __restrict__ out) {
    int j = blockIdx.x * 64 + threadIdx.x;
    int i = blockIdx.y * 4 + threadIdx.y;
    const float* arow = A + (size_t)i * K;
    float acc = b[j];
#pragma unroll 8
    for (int k = 0; k < K; ++k)
        acc = fmaf(arow[k], W[k * NOUT + j], acc);
    if (RELU) acc = fmaxf(acc, 0.0f);
    out[(size_t)i * NOUT + j] = acc;
}

// conv5 GEMM fused with bf16 hi/lo split of hs
__global__ void k_gemm_split(const float* __restrict__ A, const float* __restrict__ W,
                             const float* __restrict__ b,
                             u16* __restrict__ hi, u16* __restrict__ lo) {
    int j = blockIdx.x * 64 + threadIdx.x;
    int i = blockIdx.y * 4 + threadIdx.y;
    size_t o = (size_t)i * 256 + j;
    const float* arow = A + (size_t)i * 64;
    float acc = b[j];
#pragma unroll 8
    for (int k = 0; k < 64; ++k)
        acc = fmaf(arow[k], W[k * 256 + j], acc);
    bf16 h = __float2bfloat16(acc);
    float hf = __bfloat162float(h);
    bf16 l = __float2bfloat16(acc - hf);
    hi[o] = *(const u16*)&h;
    lo[o] = *(const u16*)&l;
}

// conv4 GEMM writing x_ with runtime out dtype
__global__ void k_gemm_out(const float* __restrict__ A, const float* __restrict__ W,
                           const float* __restrict__ b, void* __restrict__ out,
                           const int* __restrict__ flags) {
    int j = blockIdx.x * 64 + threadIdx.x;
    int i = blockIdx.y * 4 + threadIdx.y;
    const float* arow = A + (size_t)i * 64;
    float acc = b[j];
#pragma unroll 8
    for (int k = 0; k < 64; ++k)
        acc = fmaf(arow[k], W[k * 256 + j], acc);
    size_t o = (size_t)i * 256 + j;
    if (flags[0]) ((bf16*)out)[o] = __float2bfloat16(acc);
    else          ((float*)out)[o] = acc;
}

// ---------------- CSR gather aggregation (atomic-free) ----------------
// out[i][f] = selfn[i]*xw[i][f] + sum_e dinv[i]*dinv[src]*xw[src][f]  (+b, relu opt)
// one wave per node, lane per feature; 4 waves per block

template <bool BIASRELU>
__global__ __launch_bounds__(256) void k_gather(const int* __restrict__ off,
                                                const int* __restrict__ csr,
                                                const float* __restrict__ dinv,
                                                const float* __restrict__ selfn,
                                                const float* __restrict__ xw,
                                                const float* __restrict__ b,
                                                float* __restrict__ out) {
    int i = blockIdx.x * 4 + (threadIdx.x >> 6);
    int f = threadIdx.x & 63;
    float acc = selfn[i] * xw[(size_t)i * 64 + f];
    int e = off[i], end = off[i + 1];
    float di = dinv[i];
    for (; e + 2 <= end; e += 2) {          // 2-deep to overlap loads
        int s0 = csr[e], s1 = csr[e + 1];
        float w0 = di * dinv[s0], w1 = di * dinv[s1];
        float v0 = xw[(size_t)s0 * 64 + f];
        float v1 = xw[(size_t)s1 * 64 + f];
        acc = fmaf(w0, v0, acc);
        acc = fmaf(w1, v1, acc);
    }
    if (e < end) {
        int s = csr[e];
        acc = fmaf(di * dinv[s], xw[(size_t)s * 64 + f], acc);
    }
    if (BIASRELU) acc = fmaxf(acc + b[f], 0.0f);
    out[(size_t)i * 64 + f] = acc;
}

// ---------------- adj = hs @ hs^T via split-bf16 MFMA ----------------
// B-fragment col permutation: fragment v loads global col (col0 + 4*lr + v), so
// lane cc's four accumulator values (v=0..3) are CONTIGUOUS cols 4cc..4cc+3 ->
// float4 nontemporal stores (full-line, no L2 write-allocate RMW fetch).
// Bijective XCD swizzle over the 6241-tile grid for A-panel L2 locality.

__global__ __launch_bounds__(256) void k_adj_mfma(const u16* __restrict__ hi,
                                                  const u16* __restrict__ lo,
                                                  void* __restrict__ d_out,
                                                  const int* __restrict__ flags) {
    const int NT = 79 * 79, q = NT / 8, r = NT % 8;   // 6241, 780, 1
    int orig = blockIdx.x;
    int xcd = orig & 7, loc = orig >> 3;
    int tile = (xcd < r ? xcd * (q + 1) : r * (q + 1) + (xcd - r) * q) + loc;
    int by = tile / 79, bx = tile % 79;

    int wid  = threadIdx.x >> 6;
    int lane = threadIdx.x & 63;
    int wr = wid >> 1, wc = wid & 1;
    int row0 = by * 128 + wr * 64;
    int col0 = bx * 128 + wc * 64;
    int lr  = lane & 15;
    int klo = (lane >> 4) * 8;

    int aoff[4], boff[4];
#pragma unroll
    for (int u = 0; u < 4; ++u) {
        int rr = row0 + u * 16 + lr; if (rr > NN - 1) rr = NN - 1;
        aoff[u] = rr * 256 + klo;
        int c = col0 + 4 * lr + u;   if (c > NN - 1) c = NN - 1;   // permuted cols
        boff[u] = c * 256 + klo;
    }

    f32x4 acc[4][4] = {};
    for (int k0 = 0; k0 < 256; k0 += 32) {
        bf16x8 ah[4], al[4], bh[4], bl[4];
#pragma unroll
        for (int u = 0; u < 4; ++u) {
            ah[u] = *(const bf16x8*)(hi + aoff[u] + k0);
            al[u] = *(const bf16x8*)(lo + aoff[u] + k0);
            bh[u] = *(const bf16x8*)(hi + boff[u] + k0);
            bl[u] = *(const bf16x8*)(lo + boff[u] + k0);
        }
#pragma unroll
        for (int u = 0; u < 4; ++u)
#pragma unroll
            for (int v = 0; v < 4; ++v) {
                acc[u][v] = __builtin_amdgcn_mfma_f32_16x16x32_bf16(ah[u], bh[v], acc[u][v], 0, 0, 0);
                acc[u][v] = __builtin_amdgcn_mfma_f32_16x16x32_bf16(ah[u], bl[v], acc[u][v], 0, 0, 0);
                acc[u][v] = __builtin_amdgcn_mfma_f32_16x16x32_bf16(al[u], bh[v], acc[u][v], 0, 0, 0);
            }
    }

    int obf = flags[0];
    int cr = (lane >> 4) * 4;
    int cc = lane & 15;
    int j0 = col0 + 4 * cc;                 // NN%4==0 and j0%4==0 -> j0<NN implies j0+3<NN
    bf16*  ob = (bf16*)d_out + (size_t)NN * INDIM;
    float* of = (float*)d_out + (size_t)NN * INDIM;
    if (j0 < NN) {
#pragma unroll
        for (int u = 0; u < 4; ++u) {
#pragma unroll
            for (int rr = 0; rr < 4; ++rr) {
                int i = row0 + u * 16 + cr + rr;
                if (i >= NN) continue;
                if (obf) {
                    u16x4 pv;
#pragma unroll
                    for (int v = 0; v < 4; ++v) {
                        bf16 hb = __float2bfloat16(acc[u][v][rr]);
                        pv[v] = *(const u16*)&hb;
                    }
                    __builtin_nontemporal_store(pv, (u16x4*)(ob + (size_t)i * NN + j0));
                } else {
                    f32x4 pv = { acc[u][0][rr], acc[u][1][rr], acc[u][2][rr], acc[u][3][rr] };
                    __builtin_nontemporal_store(pv, (f32x4*)(of + (size_t)i * NN + j0));
                }
            }
        }
    }
}

// ---------------- driver ----------------

extern "C" void kernel_launch(void* const* d_in, const int* in_sizes, int n_in,
                              void* d_out, int out_size, void* d_ws, size_t ws_size,
                              hipStream_t stream) {
    const void* x_raw  = d_in[0];
    const void* ei_raw = d_in[1];

    const int E = in_sizes[1] / 2;

    // ---- d_ws layout (~11.9 MB, well under verified 14.4 MB) ----
    int*   flags = (int*)d_ws;
    float* wsf   = (float*)d_ws;
    float* dinv  = wsf + 16;              // 10240
    float* selfn = wsf + 10256;           // 10240
    int*   off   = (int*)(wsf + 20496);   // 10256
    int*   csr   = (int*)(wsf + 30752);   // 327680
    float* w32   = wsf + 358432;          // 58048
    u16*   hs_hi = (u16*)(wsf + 416480);  // NN*256 u16
    u16*   hs_lo = hs_hi + (size_t)NN * 256;

    float* encW1 = w32 + 0;
    float* encb1 = w32 + 16384;
    float* encW2 = w32 + 16448;
    float* encb2 = w32 + 20544;
    float* attW1 = w32 + 20608;
    float* attb1 = w32 + 24704;
    float* attW2 = w32 + 24768;
    float* attb2 = w32 + 41152;
    float* stW   = w32 + 41408;
    float* stb   = w32 + 57792;

    // ---- scratch inside adj output region (dead before k_adj writes it) ----
    float* osc  = (float*)((char*)d_out + 16000000);  // 16 MB byte offset
    float* x32  = osc;                    // 2,560,000
    float* bufA = osc + 2560000;          // 640,000
    float* bufB = osc + 3200000;          // 640,000
    float* h1   = osc + 3840000;          // 640,000
    float* h2   = osc + 4480000;          // 640,000
    float* a1   = osc + 5120000;          // 640,000
    int*   s32  = (int*)(osc + 5760000);  // 327,680
    int*   d32  = (int*)(osc + 6087680);  // 327,680
    int*   cnt  = (int*)(osc + 6415360);  // 10,240
    int*   cur  = (int*)(osc + 6425600);  // 10,240

    int eb = (E + 255) / 256;

    k_sniff<<<1, 64, 0, stream>>>((const unsigned*)x_raw, (const unsigned*)ei_raw, flags);

    // convert inputs to fp32 / int32
    k_cvt<<<10000, 256, 0, stream>>>(x_raw, x32, NN * INDIM, flags);
    k_cvt<<<64, 256, 0, stream>>>(d_in[2],  encW1, 16384, flags);
    k_cvt<<<1, 256, 0, stream>>>(d_in[3],   encb1, 64, flags);
    k_cvt<<<16, 256, 0, stream>>>(d_in[4],  encW2, 4096, flags);
    k_cvt<<<1, 256, 0, stream>>>(d_in[5],   encb2, 64, flags);
    k_cvt<<<16, 256, 0, stream>>>(d_in[6],  attW1, 4096, flags);
    k_cvt<<<1, 256, 0, stream>>>(d_in[7],   attb1, 64, flags);
    k_cvt<<<64, 256, 0, stream>>>(d_in[8],  attW2, 16384, flags);
    k_cvt<<<1, 256, 0, stream>>>(d_in[9],   attb2, 256, flags);
    k_cvt<<<64, 256, 0, stream>>>(d_in[10], stW, 16384, flags);
    k_cvt<<<1, 256, 0, stream>>>(d_in[11],  stb, 256, flags);

    // CSR build (replaces all of gcn_norm + edge arrays)
    k_zero<<<40, 256, 0, stream>>>(cnt, 10240);
    k_cvt_idx_count<<<eb, 256, 0, stream>>>(ei_raw, s32, d32, cnt, E, flags);
    k_scan<<<1, 256, 0, stream>>>(cnt, off, cur, dinv, selfn);
    k_fill<<<eb, 256, 0, stream>>>(s32, d32, cur, csr, E);

    // conv1: h1 = relu(A·(x @ encW1) + b1)
    k_gemm<256, 64><<<dim3(1, 2500), dim3(64, 4), 0, stream>>>(x32, encW1, bufA);
    k_gather<true><<<2500, 256, 0, stream>>>(off, csr, dinv, selfn, bufA, encb1, h1);

    // conv2 (reordered): h2 = (A·h1) @ encW2 + b2
    k_gather<false><<<2500, 256, 0, stream>>>(off, csr, dinv, selfn, h1, encb1, bufB);
    k_gemm_bias<64, 64, false><<<dim3(1, 2500), dim3(64, 4), 0, stream>>>(bufB, encW2, encb2, h2);

    // conv3 + conv5 share A·h2:
    k_gather<false><<<2500, 256, 0, stream>>>(off, csr, dinv, selfn, h2, encb1, bufB);
    k_gemm_bias<64, 64, true><<<dim3(1, 2500), dim3(64, 4), 0, stream>>>(bufB, attW1, attb1, a1);
    k_gemm_split<<<dim3(4, 2500), dim3(64, 4), 0, stream>>>(bufB, stW, stb, hs_hi, hs_lo);

    // conv4 (reordered): x_ = (A·a1) @ attW2 + attb2
    k_gather<false><<<2500, 256, 0, stream>>>(off, csr, dinv, selfn, a1, encb1, bufB);
    k_gemm_out<<<dim3(4, 2500), dim3(64, 4), 0, stream>>>(bufB, attW2, attb2, d_out, flags);

    // adj = hs @ hs^T
    k_adj_mfma<<<6241, 256, 0, stream>>>(hs_hi, hs_lo, d_out, flags);
}